// Round 9
// baseline (294.529 us; speedup 1.0000x reference)
//
#include <hip/hip_runtime.h>
#include <hip/hip_bf16.h>

#define N_B 4
#define SEQ 2048
#define EMB 1024
#define NH  16
#define HD  64
#define NT  (SEQ / 64)

typedef __attribute__((ext_vector_type(8))) short bf16x8;   // 8 bf16 in 4 VGPRs
typedef __attribute__((ext_vector_type(4))) short bf16x4;   // 4 bf16 in 2 VGPRs
typedef __attribute__((ext_vector_type(4))) float f32x4;
typedef unsigned int u32;
typedef unsigned long long u64;
typedef unsigned short u16;

__device__ __forceinline__ void load_lds_16B(const void* g, void* lds) {
  __builtin_amdgcn_global_load_lds(
      (const __attribute__((address_space(1))) u32*)g,
      (__attribute__((address_space(3))) u32*)lds, 16, 0, 0);
}

// pack two f32 -> two bf16 (round-to-nearest via +0x8000 before truncate)
__device__ __forceinline__ u32 pk2(float a, float b) {
  u32 au = __float_as_uint(a) + 0x8000u;
  u32 bu = __float_as_uint(b) + 0x8000u;
  return (au >> 16) | (bu & 0xFFFF0000u);
}

// ---------------- mask -> bitmask, layout [n][kb][q] (contiguous in q) ----------------
__global__ __launch_bounds__(256) void pack_mask_k(const int* __restrict__ mask,
                                                   u64* __restrict__ bits) {
  int row = blockIdx.x;                // n*SEQ + q
  int n = row >> 11, q = row & 2047;
  int lane = threadIdx.x & 63;
  int wv = threadIdx.x >> 6;
  const int* m = mask + (size_t)row * SEQ;
  for (int w = wv; w < SEQ / 64; w += 4) {
    int v = m[w * 64 + lane];
    u64 bal = __ballot(v != 0);
    if (lane == 0) bits[((size_t)n * 32 + w) * 2048 + q] = bal;
  }
}

// ---------------- remap mask bits to per-(lane,tile) u16 nibble table ----------------
// entry[(((n*32+kt)*32+qb)*4+w)*64 + lane] : bit qg*4+r = mask[q=qb*64+qg*16+(lane&15)]
//                                                        [k=kt*64+w*16+(lane>>4)*4+r]
__global__ __launch_bounds__(256) void remap_mask_k(const u64* __restrict__ bits,
                                                    u16* __restrict__ mmap) {
  int kt = blockIdx.x, qb = blockIdx.y, n = blockIdx.z;
  int t = threadIdx.x;
  int w = t >> 6, lane = t & 63;
  int l4 = lane >> 4, l15 = lane & 15;
  u32 v = 0;
#pragma unroll
  for (int qg = 0; qg < 4; ++qg) {
    u64 word = bits[((size_t)(n * 32 + kt)) * 2048 + qb * 64 + qg * 16 + l15];
    u32 nib = (u32)((word >> (w * 16 + l4 * 4)) & 0xFull);
    v |= nib << (qg * 4);
  }
  mmap[(((size_t)(n * 32 + kt) * 32 + qb) * 4 + w) * 64 + lane] = (u16)v;
}

// ---------------- fused per-head projections (q/k/v in one launch) ----------------
__global__ __launch_bounds__(256) void project3_k(const float* __restrict__ xv,
                                                  const float* __restrict__ xk,
                                                  const float* __restrict__ xq,
                                                  const float* __restrict__ Wv,
                                                  const float* __restrict__ Wk,
                                                  const float* __restrict__ Wq,
                                                  __hip_bfloat16* __restrict__ ov,
                                                  __hip_bfloat16* __restrict__ ok,
                                                  __hip_bfloat16* __restrict__ oq,
                                                  float qscale) {
  __shared__ __align__(16) float Ws4[64 * 17 * 4];  // W rows as float4, padded
  __shared__ __align__(16) float xs[1024];
  int which = blockIdx.y;
  const float* x = (which == 0) ? xv : (which == 1) ? xk : xq;
  const float* W = (which == 0) ? Wv : (which == 1) ? Wk : Wq;
  __hip_bfloat16* out = (which == 0) ? ov : (which == 1) ? ok : oq;
  float scale = (which == 2) ? qscale : 1.0f;

  int t = threadIdx.x;
  int row = blockIdx.x;            // n*SEQ + l
  int n = row >> 11, l = row & 2047;
  const float4* W4 = (const float4*)W;
#pragma unroll
  for (int i = 0; i < 4; ++i) {
    int f4 = i * 256 + t;                 // f4 = d*16 + dd4
    int d = f4 >> 4, dd4 = f4 & 15;
    *(float4*)&Ws4[(d * 17 + dd4) * 4] = W4[f4];
  }
  float4 v = ((const float4*)(x + (size_t)row * EMB))[t];
  *(float4*)&xs[t * 4] = v;
  __syncthreads();
  int d = t & 63, wv = t >> 6;
  float s[4] = {0.f, 0.f, 0.f, 0.f};
#pragma unroll
  for (int dd4 = 0; dd4 < 16; ++dd4) {
    float4 wv4 = *(const float4*)&Ws4[(d * 17 + dd4) * 4];
#pragma unroll
    for (int i = 0; i < 4; ++i) {
      float4 xv4 = *(const float4*)&xs[(i * 4 + wv) * 64 + dd4 * 4];
      s[i] += xv4.x * wv4.x + xv4.y * wv4.y + xv4.z * wv4.z + xv4.w * wv4.w;
    }
  }
#pragma unroll
  for (int i = 0; i < 4; ++i) {
    int h = i * 4 + wv;
    out[((size_t)(n * NH + h) * SEQ + l) * HD + d] = __float2bfloat16(s[i] * scale);
  }
}

// ---------------- fp32 -> bf16 copy (Wo) ----------------
__global__ __launch_bounds__(256) void cvt_bf16_k(const float* __restrict__ in,
                                                  __hip_bfloat16* __restrict__ out) {
  int i = (blockIdx.x * 256 + threadIdx.x) * 4;
  float4 v = *(const float4*)(in + i);
  out[i + 0] = __float2bfloat16(v.x);
  out[i + 1] = __float2bfloat16(v.y);
  out[i + 2] = __float2bfloat16(v.z);
  out[i + 3] = __float2bfloat16(v.w);
}

// ---------------- V transpose: vp[nh][key][d] -> vT[nh][d][granule-permuted keys] ----
// 8B granule g (4 keys) of row d stored at slot g ^ (d & 15) within each 128B tile seg.
__global__ __launch_bounds__(256) void transpose_v_k(const __hip_bfloat16* __restrict__ vp,
                                                     __hip_bfloat16* __restrict__ vT) {
  __shared__ __align__(16) u16 Ls[64 * 64];   // [key][d], XOR-swizzled 16B chunks
  int t = threadIdx.x;
  int kt = blockIdx.x, nh = blockIdx.y;
  const u16* src = (const u16*)(vp + ((size_t)nh * SEQ + kt * 64) * HD);
#pragma unroll
  for (int p = 0; p < 2; ++p) {
    int key = p * 32 + (t >> 3);
    int dc = t & 7;                         // 16B chunk within row
    uint4 vv = *(const uint4*)(src + key * 64 + dc * 8);
    *(uint4*)((char*)Ls + key * 128 + ((dc ^ (key & 7)) * 16)) = vv;
  }
  __syncthreads();
  u16* dst = (u16*)(vT + (size_t)nh * HD * SEQ);
#pragma unroll
  for (int p = 0; p < 2; ++p) {
    int d = p * 32 + (t >> 3);
    int kc = t & 7;                         // key chunk (8 keys = granules 2kc, 2kc+1)
    union { u16 s[8]; uint4 v4; } u;
#pragma unroll
    for (int j = 0; j < 8; ++j) {
      int key = kc * 8 + j;
      u.s[j] = *(const u16*)((const char*)Ls + key * 128 + (((d >> 3) ^ (key & 7)) * 16) + (d & 7) * 2);
    }
    u16* dstrow = dst + (size_t)d * SEQ + kt * 64;
    int x = d & 15;
    uint2 a = {u.v4.x, u.v4.y};
    uint2 b = {u.v4.z, u.v4.w};
    *(uint2*)(dstrow + (((2 * kc) ^ x) * 4))     = a;
    *(uint2*)(dstrow + (((2 * kc + 1) ^ x) * 4)) = b;
  }
}

// ---------------- flash attention: key-split waves ----------------
// Wave w owns keys [16w,16w+16) of every tile for ALL 64 q (Q in regs, 32 VGPR).
// Per lane-tile LDS reads: 2 b128 (K) + 4 b64 (V) = 64B (4x less than q-split).
// No online max (exp2 domain, s data-bounded << f32 overflow); partial O/rowsum
// per wave, combined once per block via LDS tree (reuses the 32KB staging buf).
__global__ __launch_bounds__(256) void attn_k(const __hip_bfloat16* __restrict__ qp,
                                              const __hip_bfloat16* __restrict__ kp,
                                              const __hip_bfloat16* __restrict__ vT,
                                              const u16* __restrict__ mmap,
                                              __hip_bfloat16* __restrict__ obuf) {
  __shared__ __align__(16) char smem[32768];   // dbuf K/V tiles; reused for reduction
#define KTB(b) (smem + (b) * 8192)
#define VTB(b) (smem + 16384 + (b) * 8192)
  int t = threadIdx.x, lane = t & 63, w = t >> 6;
  int qb = blockIdx.x, nh = blockIdx.y;
  int n = nh >> 4, h = nh & 15;
  const __hip_bfloat16* Qg = qp + ((size_t)nh * SEQ + qb * 64) * HD;
  const char* Kg = (const char*)(kp + (size_t)nh * SEQ * HD);
  const char* Vg = (const char*)(vT + (size_t)nh * HD * SEQ);
  int l15 = lane & 15, l4 = lane >> 4;
  int e7 = l15 & 7;

  // staging source offsets (pre-swizzled)
  int srow = t >> 3;
  int schunk = (t & 7) ^ (srow & 7);
  const char* gk0 = Kg + srow * 128 + schunk * 16;            // + kt*8192
  const char* gv0 = Vg + (size_t)srow * 4096 + (t & 7) * 16;  // + kt*128 (vT pre-permuted)

  // Q: all 64 q rows. qf[qg][c]: B-frag col=l15 (q=qg*16+l15), k=c*32+l4*8+j
  bf16x8 qf[4][2];
#pragma unroll
  for (int qg = 0; qg < 4; ++qg)
#pragma unroll
    for (int c = 0; c < 2; ++c)
      qf[qg][c] = *(const bf16x8*)((const char*)Qg + (qg * 16 + l15) * 128 + c * 64 + l4 * 16);

  const bf16x4 ones4 = {(short)0x3F80, (short)0x3F80, (short)0x3F80, (short)0x3F80};

  f32x4 of[4][4];     // [dt][qg] partial O^T: row d=dt*16+4*l4+r, col q=qg*16+l15
#pragma unroll
  for (int dt = 0; dt < 4; ++dt)
#pragma unroll
    for (int qg = 0; qg < 4; ++qg)
#pragma unroll
      for (int j = 0; j < 4; ++j) of[dt][qg][j] = 0.f;
  f32x4 rsacc[4];     // per-qg partial rowsum (all rows equal)
#pragma unroll
  for (int qg = 0; qg < 4; ++qg)
#pragma unroll
    for (int j = 0; j < 4; ++j) rsacc[qg][j] = 0.f;

  // mask table: one u16 per (lane, tile)
  const u16* mm = mmap + (((size_t)(n * 32) * 32 + qb) * 4 + w) * 64 + lane;

  auto STAGE = [&](int b, int kt) {
    const char* gk = gk0 + (size_t)kt * 8192;
    const char* gv = gv0 + (size_t)kt * 128;
    char* dk = KTB(b) + w * 1024;
    char* dv = VTB(b) + w * 1024;
    load_lds_16B(gk, dk);
    load_lds_16B(gk + 4096, dk + 4096);
    load_lds_16B(gv, dv);
    load_lds_16B(gv + (size_t)32 * 4096, dv + 4096);
  };

  int krow_b = (w * 16 + l15) * 128;           // K-frag row base (wave's key quarter)
  int kc0 = ((0 * 4 + l4) ^ e7) * 16;
  int kc1 = ((1 * 4 + l4) ^ e7) * 16;
  int voffB = (((w * 4 + l4) ^ l15) * 8);      // V granule slot (indep. of dt)

  // prologue
  STAGE(0, 0);
  u32 mw = mm[0];
  asm volatile("s_waitcnt vmcnt(0)" ::: "memory");
  __syncthreads();

  for (int kt = 0; kt < NT; ++kt) {
    int cur = kt & 1;
    u32 mw_nxt = 0;
    if (kt < NT - 1) {
      STAGE(cur ^ 1, kt + 1);
      mw_nxt = mm[(size_t)(kt + 1) * 8192];
    }
    const char* KB = KTB(cur);
    const char* VB = VTB(cur);

    // ---- K frags for wave's 16 keys (reused across all 4 q-groups)
    bf16x8 ak0 = *(const bf16x8*)(KB + krow_b + kc0);
    bf16x8 ak1 = *(const bf16x8*)(KB + krow_b + kc1);
    // ---- S^T = K Q^T (exp2 domain): lane -> S^T[key=16w+4*l4+r][q=qg*16+l15]
    f32x4 sf[4];
#pragma unroll
    for (int qg = 0; qg < 4; ++qg)
#pragma unroll
      for (int j = 0; j < 4; ++j) sf[qg][j] = 0.f;
#pragma unroll
    for (int qg = 0; qg < 4; ++qg)
      sf[qg] = __builtin_amdgcn_mfma_f32_16x16x32_bf16(ak0, qf[qg][0], sf[qg], 0, 0, 0);
#pragma unroll
    for (int qg = 0; qg < 4; ++qg)
      sf[qg] = __builtin_amdgcn_mfma_f32_16x16x32_bf16(ak1, qf[qg][1], sf[qg], 0, 0, 0);

    // ---- p = exp2(s), mask-zero (nibble qg: bit r), pack to bf16 B-frags
    bf16x4 pbq[4];
#pragma unroll
    for (int qg = 0; qg < 4; ++qg) {
      u32 sel = (mw >> (qg * 4)) & 0xFu;
      float p0 = __builtin_amdgcn_exp2f(sf[qg][0]);
      float p1 = __builtin_amdgcn_exp2f(sf[qg][1]);
      float p2 = __builtin_amdgcn_exp2f(sf[qg][2]);
      float p3 = __builtin_amdgcn_exp2f(sf[qg][3]);
      p0 = (sel & 1u) ? p0 : 0.f;
      p1 = (sel & 2u) ? p1 : 0.f;
      p2 = (sel & 4u) ? p2 : 0.f;
      p3 = (sel & 8u) ? p3 : 0.f;
      union { u32 u[2]; bf16x4 s; } pu;
      pu.u[0] = pk2(p0, p1);
      pu.u[1] = pk2(p2, p3);
      pbq[qg] = pu.s;
    }
    // ---- partial rowsum via K16 MFMA
#pragma unroll
    for (int qg = 0; qg < 4; ++qg)
      rsacc[qg] = __builtin_amdgcn_mfma_f32_16x16x16bf16_1k(ones4, pbq[qg], rsacc[qg], 0, 0, 0);
    // ---- partial O^T += V^T P (one b64 V granule per dt, reused across qg)
#pragma unroll
    for (int dt = 0; dt < 4; ++dt) {
      bf16x4 av = *(const bf16x4*)(VB + (dt * 16 + l15) * 128 + voffB);
#pragma unroll
      for (int qg = 0; qg < 4; ++qg)
        of[dt][qg] = __builtin_amdgcn_mfma_f32_16x16x16bf16_1k(av, pbq[qg], of[dt][qg], 0, 0, 0);
    }

    mw = mw_nxt;
    if (kt < NT - 1) {
      asm volatile("s_waitcnt vmcnt(0)" ::: "memory");   // next-tile stage landed
      __syncthreads();
    }
  }

  // ---- cross-wave combine (exact sums; no max state). Reuse smem.
  __syncthreads();                      // everyone done with K/V tiles
  float* redrs = (float*)smem;          // [w*4+qg][l15]
  if (l4 == 0) {
#pragma unroll
    for (int qg = 0; qg < 4; ++qg) redrs[(w * 4 + qg) * 16 + l15] = rsacc[qg][0];
  }
  __syncthreads();
  float inv[4];
#pragma unroll
  for (int qg = 0; qg < 4; ++qg) {
    float s = redrs[(0 + qg) * 16 + l15] + redrs[(4 + qg) * 16 + l15] +
              redrs[(8 + qg) * 16 + l15] + redrs[(12 + qg) * 16 + l15];
    inv[qg] = 1.f / s;
  }
  __syncthreads();
  float* red = (float*)smem;            // [w][s][i=4*l4+r][q] = 8192 floats (32KB)
#pragma unroll
  for (int rnd = 0; rnd < 2; ++rnd) {
#pragma unroll
    for (int s = 0; s < 2; ++s) {
      int dt = rnd * 2 + s;
#pragma unroll
      for (int qg = 0; qg < 4; ++qg)
#pragma unroll
        for (int r = 0; r < 4; ++r)
          red[((w * 2 + s) * 16 + l4 * 4 + r) * 64 + qg * 16 + l15] = of[dt][qg][r];
    }
    __syncthreads();
    if (w < 2) {
      int dt = rnd * 2 + w;             // wave 0 sums s=0, wave 1 sums s=1
#pragma unroll
      for (int qg = 0; qg < 4; ++qg) {
        float o[4];
#pragma unroll
        for (int r = 0; r < 4; ++r) {
          int idx = (w * 16 + l4 * 4 + r) * 64 + qg * 16 + l15;
          o[r] = red[idx] + red[idx + 32 * 64] + red[idx + 64 * 64] + red[idx + 96 * 64];
        }
        uint2 v2 = {pk2(o[0] * inv[qg], o[1] * inv[qg]),
                    pk2(o[2] * inv[qg], o[3] * inv[qg])};
        *(uint2*)(obuf + ((size_t)n * SEQ + qb * 64 + qg * 16 + l15) * EMB +
                  h * HD + dt * 16 + l4 * 4) = v2;
      }
    }
    if (rnd == 0) __syncthreads();
  }
#undef KTB
#undef VTB
}

// ---------------- output GEMM: double-buffered, chunk-swizzled ----------------
__global__ __launch_bounds__(256) void out_gemm_k(const __hip_bfloat16* __restrict__ A,
                                                  const __hip_bfloat16* __restrict__ Bw,
                                                  const float* __restrict__ bias,
                                                  float* __restrict__ Y) {
  __shared__ __align__(16) __hip_bfloat16 As[2][128 * 32];
  __shared__ __align__(16) __hip_bfloat16 Bs[2][128 * 32];
  int t = threadIdx.x, lane = t & 63, w = t >> 6;
  int l15 = lane & 15, l4 = lane >> 4;
  int bm = blockIdx.x * 128, bn = blockIdx.y * 128;
  int wr = w >> 1, wc = w & 1;
  f32x4 acc[4][4];
#pragma unroll
  for (int m = 0; m < 4; ++m)
#pragma unroll
    for (int nn = 0; nn < 4; ++nn)
#pragma unroll
      for (int j = 0; j < 4; ++j) acc[m][nn][j] = 0.f;

  int srow = t >> 2;                        // LDS row 0..63 (row stride 64B)
  int schunk = (t & 3) ^ (srow & 3);        // source 16B chunk pre-swizzle

  auto STAGE = [&](int b, int kt) {
    const char* ga = (const char*)(A + (size_t)(bm + srow) * 1024 + kt * 32) + schunk * 16;
    char* da = (char*)&As[b][0] + w * 1024;
    load_lds_16B(ga, da);
    load_lds_16B(ga + (size_t)64 * 2048, da + 4096);   // rows +64: same (row&3)
    const char* gb = (const char*)(Bw + (size_t)(bn + srow) * 1024 + kt * 32) + schunk * 16;
    char* db = (char*)&Bs[b][0] + w * 1024;
    load_lds_16B(gb, db);
    load_lds_16B(gb + (size_t)64 * 2048, db + 4096);
  };

  STAGE(0, 0);
  asm volatile("s_waitcnt vmcnt(0)" ::: "memory");
  __syncthreads();

#pragma unroll 2
  for (int kt = 0; kt < 32; ++kt) {
    int cur = kt & 1;
    if (kt < 31) STAGE(cur ^ 1, kt + 1);
    const char* AB = (const char*)&As[cur][0];
    const char* BB = (const char*)&Bs[cur][0];
    bf16x8 af[4], bfr[4];
#pragma unroll
    for (int m = 0; m < 4; ++m) {
      int arow = wr * 64 + m * 16 + l15;
      af[m] = *(const bf16x8*)(AB + arow * 64 + ((l4 ^ (arow & 3)) * 16));
    }
#pragma unroll
    for (int nn = 0; nn < 4; ++nn) {
      int brow = wc * 64 + nn * 16 + l15;
      bfr[nn] = *(const bf16x8*)(BB + brow * 64 + ((l4 ^ (brow & 3)) * 16));
    }
#pragma unroll
    for (int m = 0; m < 4; ++m)
#pragma unroll
      for (int nn = 0; nn < 4; ++nn)
        acc[m][nn] = __builtin_amdgcn_mfma_f32_16x16x32_bf16(af[m], bfr[nn], acc[m][nn], 0, 0, 0);
    if (kt < 31) {
      asm volatile("s_waitcnt vmcnt(0)" ::: "memory");
      __syncthreads();
    }
  }
#pragma unroll
  for (int m = 0; m < 4; ++m)
#pragma unroll
    for (int nn = 0; nn < 4; ++nn)
#pragma unroll
      for (int r = 0; r < 4; ++r) {
        int row = bm + wr * 64 + m * 16 + l4 * 4 + r;
        int col = bn + wc * 64 + nn * 16 + l15;
        Y[(size_t)row * 1024 + col] = acc[m][nn][r] + bias[col];
      }
}

extern "C" void kernel_launch(void* const* d_in, const int* in_sizes, int n_in,
                              void* d_out, int out_size, void* d_ws, size_t ws_size,
                              hipStream_t stream) {
  const float* values  = (const float*)d_in[0];
  const float* keys    = (const float*)d_in[1];
  const float* queries = (const float*)d_in[2];
  const int*   mask    = (const int*)d_in[3];
  const float* Wv      = (const float*)d_in[4];
  const float* Wk      = (const float*)d_in[5];
  const float* Wq      = (const float*)d_in[6];
  const float* Wo      = (const float*)d_in[7];
  const float* bo      = (const float*)d_in[8];
  float* out = (float*)d_out;

  char* ws = (char*)d_ws;
  __hip_bfloat16* qp   = (__hip_bfloat16*)(ws);
  __hip_bfloat16* kp   = (__hip_bfloat16*)(ws + (size_t)16 * 1024 * 1024);
  __hip_bfloat16* vp   = (__hip_bfloat16*)(ws + (size_t)32 * 1024 * 1024);
  __hip_bfloat16* obuf = (__hip_bfloat16*)(ws + (size_t)48 * 1024 * 1024);
  u64*            mbts = (u64*)           (ws + (size_t)64 * 1024 * 1024);
  __hip_bfloat16* wob  = (__hip_bfloat16*)(ws + (size_t)66 * 1024 * 1024);
  u16*            mmap = (u16*)           (ws + (size_t)72 * 1024 * 1024);
  __hip_bfloat16* vTp  = (__hip_bfloat16*)(ws + (size_t)80 * 1024 * 1024);

  // Q pre-scale: (1/sqrt(EMB)) * log2(e) so attn softmax runs in exp2 domain
  const float qscale = 0.03125f * 1.44269504088896340736f;

  pack_mask_k<<<dim3(N_B * SEQ), 256, 0, stream>>>(mask, mbts);
  remap_mask_k<<<dim3(32, 32, N_B), 256, 0, stream>>>(mbts, mmap);
  project3_k<<<dim3(N_B * SEQ, 3), 256, 0, stream>>>(values, keys, queries,
                                                     Wv, Wk, Wq, vp, kp, qp, qscale);
  transpose_v_k<<<dim3(SEQ / 64, N_B * NH), 256, 0, stream>>>(vp, vTp);
  cvt_bf16_k<<<dim3(1024), 256, 0, stream>>>(Wo, wob);
  attn_k<<<dim3(SEQ / 64, N_B * NH), 256, 0, stream>>>(qp, kp, vTp, mmap, obuf);
  out_gemm_k<<<dim3(64, 8), 256, 0, stream>>>(obuf, wob, bo, out);
}

// Round 11
// 262.098 us; speedup vs baseline: 1.1237x; 1.1237x over previous
//
#include <hip/hip_runtime.h>
#include <hip/hip_bf16.h>

#define N_B 4
#define SEQ 2048
#define EMB 1024
#define NH  16
#define HD  64
#define NT  (SEQ / 64)

typedef __attribute__((ext_vector_type(8))) short bf16x8;   // 8 bf16 in 4 VGPRs
typedef __attribute__((ext_vector_type(4))) short bf16x4;   // 4 bf16 in 2 VGPRs
typedef __attribute__((ext_vector_type(4))) float f32x4;
typedef unsigned int u32;
typedef unsigned long long u64;
typedef unsigned short u16;

__device__ __forceinline__ void load_lds_16B(const void* g, void* lds) {
  __builtin_amdgcn_global_load_lds(
      (const __attribute__((address_space(1))) u32*)g,
      (__attribute__((address_space(3))) u32*)lds, 16, 0, 0);
}

// pack two f32 -> two bf16 (round-to-nearest via +0x8000 before truncate)
__device__ __forceinline__ u32 pk2(float a, float b) {
  u32 au = __float_as_uint(a) + 0x8000u;
  u32 bu = __float_as_uint(b) + 0x8000u;
  return (au >> 16) | (bu & 0xFFFF0000u);
}

__device__ __forceinline__ float m3(float a, float b, float c) {
  return fmaxf(fmaxf(a, b), c);   // clang fuses to v_max3_f32
}

// ---------------- mask -> bitmask, layout [n][kb][q] (contiguous in q) ----------------
__global__ __launch_bounds__(256) void pack_mask_k(const int* __restrict__ mask,
                                                   u64* __restrict__ bits) {
  int row = blockIdx.x;                // n*SEQ + q
  int n = row >> 11, q = row & 2047;
  int lane = threadIdx.x & 63;
  int wv = threadIdx.x >> 6;
  const int* m = mask + (size_t)row * SEQ;
  for (int w = wv; w < SEQ / 64; w += 4) {
    int v = m[w * 64 + lane];
    u64 bal = __ballot(v != 0);
    if (lane == 0) bits[((size_t)n * 32 + w) * 2048 + q] = bal;
  }
}

// ---------------- fused per-head projections (q/k/v in one launch) ----------------
__global__ __launch_bounds__(256) void project3_k(const float* __restrict__ xv,
                                                  const float* __restrict__ xk,
                                                  const float* __restrict__ xq,
                                                  const float* __restrict__ Wv,
                                                  const float* __restrict__ Wk,
                                                  const float* __restrict__ Wq,
                                                  __hip_bfloat16* __restrict__ ov,
                                                  __hip_bfloat16* __restrict__ ok,
                                                  __hip_bfloat16* __restrict__ oq,
                                                  float qscale) {
  __shared__ __align__(16) float Ws4[64 * 17 * 4];  // W rows as float4, padded
  __shared__ __align__(16) float xs[1024];
  int which = blockIdx.y;
  const float* x = (which == 0) ? xv : (which == 1) ? xk : xq;
  const float* W = (which == 0) ? Wv : (which == 1) ? Wk : Wq;
  __hip_bfloat16* out = (which == 0) ? ov : (which == 1) ? ok : oq;
  float scale = (which == 2) ? qscale : 1.0f;

  int t = threadIdx.x;
  int row = blockIdx.x;            // n*SEQ + l
  int n = row >> 11, l = row & 2047;
  const float4* W4 = (const float4*)W;
#pragma unroll
  for (int i = 0; i < 4; ++i) {
    int f4 = i * 256 + t;                 // f4 = d*16 + dd4
    int d = f4 >> 4, dd4 = f4 & 15;
    *(float4*)&Ws4[(d * 17 + dd4) * 4] = W4[f4];
  }
  float4 v = ((const float4*)(x + (size_t)row * EMB))[t];
  *(float4*)&xs[t * 4] = v;
  __syncthreads();
  int d = t & 63, wv = t >> 6;
  float s[4] = {0.f, 0.f, 0.f, 0.f};
#pragma unroll
  for (int dd4 = 0; dd4 < 16; ++dd4) {
    float4 wv4 = *(const float4*)&Ws4[(d * 17 + dd4) * 4];
#pragma unroll
    for (int i = 0; i < 4; ++i) {
      float4 xv4 = *(const float4*)&xs[(i * 4 + wv) * 64 + dd4 * 4];
      s[i] += xv4.x * wv4.x + xv4.y * wv4.y + xv4.z * wv4.z + xv4.w * wv4.w;
    }
  }
#pragma unroll
  for (int i = 0; i < 4; ++i) {
    int h = i * 4 + wv;
    out[((size_t)(n * NH + h) * SEQ + l) * HD + d] = __float2bfloat16(s[i] * scale);
  }
}

// ---------------- fp32 -> bf16 copy (Wo) ----------------
__global__ __launch_bounds__(256) void cvt_bf16_k(const float* __restrict__ in,
                                                  __hip_bfloat16* __restrict__ out) {
  int i = (blockIdx.x * 256 + threadIdx.x) * 4;
  float4 v = *(const float4*)(in + i);
  out[i + 0] = __float2bfloat16(v.x);
  out[i + 1] = __float2bfloat16(v.y);
  out[i + 2] = __float2bfloat16(v.z);
  out[i + 3] = __float2bfloat16(v.w);
}

// ---------------- V transpose: vp[nh][key][d] -> vT[nh][d][granule-permuted keys] ----
// 8B granule g (4 keys) of row d stored at slot g ^ (d & 15) within each 128B tile seg.
__global__ __launch_bounds__(256) void transpose_v_k(const __hip_bfloat16* __restrict__ vp,
                                                     __hip_bfloat16* __restrict__ vT) {
  __shared__ __align__(16) u16 Ls[64 * 64];   // [key][d], XOR-swizzled 16B chunks
  int t = threadIdx.x;
  int kt = blockIdx.x, nh = blockIdx.y;
  const u16* src = (const u16*)(vp + ((size_t)nh * SEQ + kt * 64) * HD);
#pragma unroll
  for (int p = 0; p < 2; ++p) {
    int key = p * 32 + (t >> 3);
    int dc = t & 7;                         // 16B chunk within row
    uint4 vv = *(const uint4*)(src + key * 64 + dc * 8);
    *(uint4*)((char*)Ls + key * 128 + ((dc ^ (key & 7)) * 16)) = vv;
  }
  __syncthreads();
  u16* dst = (u16*)(vT + (size_t)nh * HD * SEQ);
#pragma unroll
  for (int p = 0; p < 2; ++p) {
    int d = p * 32 + (t >> 3);
    int kc = t & 7;                         // key chunk (8 keys = granules 2kc, 2kc+1)
    union { u16 s[8]; uint4 v4; } u;
#pragma unroll
    for (int j = 0; j < 8; ++j) {
      int key = kc * 8 + j;
      u.s[j] = *(const u16*)((const char*)Ls + key * 128 + (((d >> 3) ^ (key & 7)) * 16) + (d & 7) * 2);
    }
    u16* dstrow = dst + (size_t)d * SEQ + kt * 64;
    int x = d & 15;
    uint2 a = {u.v4.x, u.v4.y};
    uint2 b = {u.v4.z, u.v4.w};
    *(uint2*)(dstrow + (((2 * kc) ^ x) * 4))     = a;
    *(uint2*)(dstrow + (((2 * kc + 1) ^ x) * 4)) = b;
  }
}

// ---------------- flash attention (R8 structure + XCD-aware block swizzle) ----------------
// S^T swapped ops, register P, dbuf LDS, -m-seeded QK accumulator, defer-max
// THR=8 (rescale branch ~never taken), cross-tile MFMA row-sum, mask prefetch.
// Block swizzle: XCD a (= flat%8 round-robin) runs heads [8a,8a+8), with all 32
// q-blocks of one head consecutive on that XCD -> K/V (512KB/head) L2-resident.
__global__ __launch_bounds__(256) void attn_k(const __hip_bfloat16* __restrict__ qp,
                                              const __hip_bfloat16* __restrict__ kp,
                                              const __hip_bfloat16* __restrict__ vT,
                                              const u64* __restrict__ mbits,
                                              __hip_bfloat16* __restrict__ obuf) {
  __shared__ __align__(16) __hip_bfloat16 Kt[2][64 * 64];    // [key][kdim] chunk-swz
  __shared__ __align__(16) __hip_bfloat16 Vt[2][64 * 64];    // [d][key] granule-swz
  int t = threadIdx.x, lane = t & 63, w = t >> 6;
  // XCD swizzle (bijective rotation of the flat block id)
  int flat = blockIdx.y * 32 + blockIdx.x;
  int nf = (flat & 7) * 256 + (flat >> 3);
  int qb = nf & 31, nh = nf >> 5;
  int n = nh >> 4, h = nh & 15;
  const __hip_bfloat16* Qg = qp + ((size_t)nh * SEQ + qb * 64) * HD;
  const char* Kg = (const char*)(kp + (size_t)nh * SEQ * HD);
  const char* Vg = (const char*)(vT + (size_t)nh * HD * SEQ);
  int l15 = lane & 15, l4 = lane >> 4;
  int e7 = l15 & 7;

  int srow = t >> 3;
  int schunk = (t & 7) ^ (srow & 7);       // K-tile source pre-swizzle (16B chunks)

  // Q B-frag: col=l15 (q=w*16+l15), k = 32c + l4*8 + j
  bf16x8 qf[2];
#pragma unroll
  for (int c = 0; c < 2; ++c)
    qf[c] = *(const bf16x8*)(Qg + (size_t)(w * 16 + l15) * HD + c * 32 + l4 * 8);

  const bf16x4 ones4 = {(short)0x3F80, (short)0x3F80, (short)0x3F80, (short)0x3F80};

  f32x4 of[4];
#pragma unroll
  for (int dt = 0; dt < 4; ++dt)
#pragma unroll
    for (int j = 0; j < 4; ++j) of[dt][j] = 0.f;
  f32x4 rs = {0.f, 0.f, 0.f, 0.f};   // cross-tile row-sum accumulator (all rows equal)
  float negm = 0.f;                  // = -m; m starts at 0 (defer-max reference)

  int q = qb * 64 + w * 16 + l15;

  // staging base pointers (per-tile offsets added in STAGE)
  const char* gk0 = Kg + srow * 128 + schunk * 16;            // + kt*8192
  const char* gv0 = Vg + (size_t)srow * 4096 + (t & 7) * 16;  // + kt*128

  auto STAGE = [&](int b, int kt) {
    const char* gk = gk0 + (size_t)kt * 8192;
    const char* gv = gv0 + (size_t)kt * 128;
    char* dk = (char*)&Kt[b][0] + w * 1024;
    char* dv = (char*)&Vt[b][0] + w * 1024;
    load_lds_16B(gk, dk);
    load_lds_16B(gk + 4096, dk + 4096);
    load_lds_16B(gv, dv);
    load_lds_16B(gv + (size_t)32 * 4096, dv + 4096);
  };

  // PV A-frag granule offsets: byte = row*128 + ((ct*4+l4)^l15)*8
  int voff[4];
#pragma unroll
  for (int ct = 0; ct < 4; ++ct)
    voff[ct] = (((ct * 4 + l4) ^ l15) * 8);

  // prologue
  const u64* mptr = mbits + (size_t)n * 32 * 2048 + q;
  STAGE(0, 0);
  u64 mw = mptr[0];
  asm volatile("s_waitcnt vmcnt(0)" ::: "memory");
  __syncthreads();

#pragma unroll 2
  for (int kt = 0; kt < NT; ++kt) {
    int cur = kt & 1;
    u64 mw_nxt = 0;
    if (kt < NT - 1) {
      STAGE(cur ^ 1, kt + 1);
      mw_nxt = mptr[(size_t)(kt + 1) * 2048];   // prefetch next tile's mask word
    }
    const char* KB = (const char*)&Kt[cur][0];
    const char* VB = (const char*)&Vt[cur][0];

    // ---- S^T = K Q^T, accumulator seeded with -m => sf = s - m after MFMA
    f32x4 sf[4];
#pragma unroll
    for (int ct = 0; ct < 4; ++ct)
#pragma unroll
      for (int j = 0; j < 4; ++j) sf[ct][j] = negm;
#pragma unroll
    for (int c = 0; c < 2; ++c) {
#pragma unroll
      for (int ct = 0; ct < 4; ++ct) {
        int krow = ct * 16 + l15;
        bf16x8 ak = *(const bf16x8*)(KB + krow * 128 + (((c * 4 + l4) ^ e7) * 16));
        sf[ct] = __builtin_amdgcn_mfma_f32_16x16x32_bf16(ak, qf[c], sf[ct], 0, 0, 0);
      }
    }

    // ---- defer-max: rescale only if some lane's tile max exceeds THR=8
    float t0 = m3(sf[0][0], sf[0][1], sf[0][2]);
    float t1 = m3(sf[0][3], sf[1][0], sf[1][1]);
    float t2 = m3(sf[1][2], sf[1][3], sf[2][0]);
    float t3 = m3(sf[2][1], sf[2][2], sf[2][3]);
    float t4 = m3(sf[3][0], sf[3][1], sf[3][2]);
    float tmax = fmaxf(m3(t0, t1, t2), m3(t3, t4, sf[3][3]));
    if (__any(tmax > 8.f)) {
      float tm = fmaxf(tmax, __shfl_xor(tmax, 16));
      tm = fmaxf(tm, __shfl_xor(tm, 32));
      float d = fmaxf(tm, 0.f);                 // per-q delta (0 if no new max)
      float corr = __builtin_amdgcn_exp2f(-d);
      negm -= d;
#pragma unroll
      for (int j = 0; j < 4; ++j) rs[j] *= corr;
#pragma unroll
      for (int dt = 0; dt < 4; ++dt)
#pragma unroll
        for (int r = 0; r < 4; ++r) of[dt][r] *= corr;
#pragma unroll
      for (int ct = 0; ct < 4; ++ct)
#pragma unroll
        for (int r = 0; r < 4; ++r) sf[ct][r] -= d;
    }
    // ---- p = exp2(sf) (<= 2^8), mask-zero (bit 16ct + 4*l4 + r), pack to bf16
    u64 m4 = mw >> (l4 * 4);
    u32 c0 = (u32)m4, c1 = (u32)(m4 >> 32);
    bf16x4 pbq[4];
#pragma unroll
    for (int ct = 0; ct < 4; ++ct) {
      u32 sel = (ct & 2) ? c1 : c0;
      u32 base = (ct & 1) ? 0x10000u : 1u;
      float p0 = __builtin_amdgcn_exp2f(sf[ct][0]);
      float p1 = __builtin_amdgcn_exp2f(sf[ct][1]);
      float p2 = __builtin_amdgcn_exp2f(sf[ct][2]);
      float p3 = __builtin_amdgcn_exp2f(sf[ct][3]);
      p0 = (sel & (base << 0)) ? p0 : 0.f;
      p1 = (sel & (base << 1)) ? p1 : 0.f;
      p2 = (sel & (base << 2)) ? p2 : 0.f;
      p3 = (sel & (base << 3)) ? p3 : 0.f;
      union { u32 u[2]; bf16x4 s; } pu;
      pu.u[0] = pk2(p0, p1);
      pu.u[1] = pk2(p2, p3);
      pbq[ct] = pu.s;
    }
    // ---- row-sum accumulates across tiles (A = ones => all C rows identical)
#pragma unroll
    for (int ct = 0; ct < 4; ++ct)
      rs = __builtin_amdgcn_mfma_f32_16x16x16bf16_1k(ones4, pbq[ct], rs, 0, 0, 0);
    // ---- O^T += V^T P : A = V^T b64 granule frags (conflict-free), B = register P
#pragma unroll
    for (int dt = 0; dt < 4; ++dt) {
      int vrow_b = (dt * 16 + l15) * 128;
#pragma unroll
      for (int ct = 0; ct < 4; ++ct) {
        bf16x4 av = *(const bf16x4*)(VB + vrow_b + voff[ct]);
        of[dt] = __builtin_amdgcn_mfma_f32_16x16x16bf16_1k(av, pbq[ct], of[dt], 0, 0, 0);
      }
    }

    mw = mw_nxt;
    if (kt < NT - 1) {
      asm volatile("s_waitcnt vmcnt(0)" ::: "memory");   // next-tile stage landed
      __syncthreads();
    }
  }
  // ---- epilogue: lane owns q; d = 16dt + 4*l4 + r (8B packed stores)
  float inv = 1.f / rs[0];
  size_t obase = ((size_t)n * SEQ + q) * EMB + h * HD;
#pragma unroll
  for (int dt = 0; dt < 4; ++dt) {
    uint2 v2 = {pk2(of[dt][0] * inv, of[dt][1] * inv),
                pk2(of[dt][2] * inv, of[dt][3] * inv)};
    *(uint2*)(obuf + obase + dt * 16 + l4 * 4) = v2;
  }
}

// ---------------- output GEMM: double-buffered, chunk-swizzled ----------------
__global__ __launch_bounds__(256) void out_gemm_k(const __hip_bfloat16* __restrict__ A,
                                                  const __hip_bfloat16* __restrict__ Bw,
                                                  const float* __restrict__ bias,
                                                  float* __restrict__ Y) {
  __shared__ __align__(16) __hip_bfloat16 As[2][128 * 32];
  __shared__ __align__(16) __hip_bfloat16 Bs[2][128 * 32];
  int t = threadIdx.x, lane = t & 63, w = t >> 6;
  int l15 = lane & 15, l4 = lane >> 4;
  int bm = blockIdx.x * 128, bn = blockIdx.y * 128;
  int wr = w >> 1, wc = w & 1;
  f32x4 acc[4][4];
#pragma unroll
  for (int m = 0; m < 4; ++m)
#pragma unroll
    for (int nn = 0; nn < 4; ++nn)
#pragma unroll
      for (int j = 0; j < 4; ++j) acc[m][nn][j] = 0.f;

  int srow = t >> 2;                        // LDS row 0..63 (row stride 64B)
  int schunk = (t & 3) ^ (srow & 3);        // source 16B chunk pre-swizzle

  auto STAGE = [&](int b, int kt) {
    const char* ga = (const char*)(A + (size_t)(bm + srow) * 1024 + kt * 32) + schunk * 16;
    char* da = (char*)&As[b][0] + w * 1024;
    load_lds_16B(ga, da);
    load_lds_16B(ga + (size_t)64 * 2048, da + 4096);   // rows +64: same (row&3)
    const char* gb = (const char*)(Bw + (size_t)(bn + srow) * 1024 + kt * 32) + schunk * 16;
    char* db = (char*)&Bs[b][0] + w * 1024;
    load_lds_16B(gb, db);
    load_lds_16B(gb + (size_t)64 * 2048, db + 4096);
  };

  STAGE(0, 0);
  asm volatile("s_waitcnt vmcnt(0)" ::: "memory");
  __syncthreads();

#pragma unroll 2
  for (int kt = 0; kt < 32; ++kt) {
    int cur = kt & 1;
    if (kt < 31) STAGE(cur ^ 1, kt + 1);
    const char* AB = (const char*)&As[cur][0];
    const char* BB = (const char*)&Bs[cur][0];
    bf16x8 af[4], bfr[4];
#pragma unroll
    for (int m = 0; m < 4; ++m) {
      int arow = wr * 64 + m * 16 + l15;
      af[m] = *(const bf16x8*)(AB + arow * 64 + ((l4 ^ (arow & 3)) * 16));
    }
#pragma unroll
    for (int nn = 0; nn < 4; ++nn) {
      int brow = wc * 64 + nn * 16 + l15;
      bfr[nn] = *(const bf16x8*)(BB + brow * 64 + ((l4 ^ (brow & 3)) * 16));
    }
#pragma unroll
    for (int m = 0; m < 4; ++m)
#pragma unroll
      for (int nn = 0; nn < 4; ++nn)
        acc[m][nn] = __builtin_amdgcn_mfma_f32_16x16x32_bf16(af[m], bfr[nn], acc[m][nn], 0, 0, 0);
    if (kt < 31) {
      asm volatile("s_waitcnt vmcnt(0)" ::: "memory");
      __syncthreads();
    }
  }
#pragma unroll
  for (int m = 0; m < 4; ++m)
#pragma unroll
    for (int nn = 0; nn < 4; ++nn)
#pragma unroll
      for (int r = 0; r < 4; ++r) {
        int row = bm + wr * 64 + m * 16 + l4 * 4 + r;
        int col = bn + wc * 64 + nn * 16 + l15;
        Y[(size_t)row * 1024 + col] = acc[m][nn][r] + bias[col];
      }
}

extern "C" void kernel_launch(void* const* d_in, const int* in_sizes, int n_in,
                              void* d_out, int out_size, void* d_ws, size_t ws_size,
                              hipStream_t stream) {
  const float* values  = (const float*)d_in[0];
  const float* keys    = (const float*)d_in[1];
  const float* queries = (const float*)d_in[2];
  const int*   mask    = (const int*)d_in[3];
  const float* Wv      = (const float*)d_in[4];
  const float* Wk      = (const float*)d_in[5];
  const float* Wq      = (const float*)d_in[6];
  const float* Wo      = (const float*)d_in[7];
  const float* bo      = (const float*)d_in[8];
  float* out = (float*)d_out;

  char* ws = (char*)d_ws;
  __hip_bfloat16* qp   = (__hip_bfloat16*)(ws);
  __hip_bfloat16* kp   = (__hip_bfloat16*)(ws + (size_t)16 * 1024 * 1024);
  __hip_bfloat16* vp   = (__hip_bfloat16*)(ws + (size_t)32 * 1024 * 1024);
  __hip_bfloat16* obuf = (__hip_bfloat16*)(ws + (size_t)48 * 1024 * 1024);
  u64*            mbts = (u64*)           (ws + (size_t)64 * 1024 * 1024);
  __hip_bfloat16* wob  = (__hip_bfloat16*)(ws + (size_t)66 * 1024 * 1024);
  __hip_bfloat16* vTp  = (__hip_bfloat16*)(ws + (size_t)80 * 1024 * 1024);

  // Q pre-scale: (1/sqrt(EMB)) * log2(e) so attn softmax runs in exp2 domain
  const float qscale = 0.03125f * 1.44269504088896340736f;

  pack_mask_k<<<dim3(N_B * SEQ), 256, 0, stream>>>(mask, mbts);
  project3_k<<<dim3(N_B * SEQ, 3), 256, 0, stream>>>(values, keys, queries,
                                                     Wv, Wk, Wq, vp, kp, qp, qscale);
  transpose_v_k<<<dim3(SEQ / 64, N_B * NH), 256, 0, stream>>>(vp, vTp);
  cvt_bf16_k<<<dim3(1024), 256, 0, stream>>>(Wo, wob);
  attn_k<<<dim3(32, 64), 256, 0, stream>>>(qp, kp, vTp, mbts, obuf);
  out_gemm_k<<<dim3(64, 8), 256, 0, stream>>>(obuf, wob, bo, out);
}

// Round 13
// 258.847 us; speedup vs baseline: 1.1379x; 1.0126x over previous
//
#include <hip/hip_runtime.h>
#include <hip/hip_bf16.h>

#define N_B 4
#define SEQ 2048
#define EMB 1024
#define NH  16
#define HD  64
#define NT  (SEQ / 64)

typedef __attribute__((ext_vector_type(8))) short bf16x8;   // 8 bf16 in 4 VGPRs
typedef __attribute__((ext_vector_type(4))) short bf16x4;   // 4 bf16 in 2 VGPRs
typedef __attribute__((ext_vector_type(4))) float f32x4;
typedef unsigned int u32;
typedef unsigned long long u64;
typedef unsigned short u16;

__device__ __forceinline__ void load_lds_16B(const void* g, void* lds) {
  __builtin_amdgcn_global_load_lds(
      (const __attribute__((address_space(1))) u32*)g,
      (__attribute__((address_space(3))) u32*)lds, 16, 0, 0);
}

// pack two f32 -> two bf16 (round-to-nearest via +0x8000 before truncate)
__device__ __forceinline__ u32 pk2(float a, float b) {
  u32 au = __float_as_uint(a) + 0x8000u;
  u32 bu = __float_as_uint(b) + 0x8000u;
  return (au >> 16) | (bu & 0xFFFF0000u);
}

__device__ __forceinline__ float m3(float a, float b, float c) {
  return fmaxf(fmaxf(a, b), c);   // clang fuses to v_max3_f32
}

// ---------------- fused pre-pass ----------------
// blockIdx.y = 0/1/2: per-head projections of values/keys/queries (R11-proven
// 17-pad W layout — 2-way bank conflicts, free). blockIdx.y = 3: mask->bitmask
// pack (+ Wo fp32->bf16 cvt on first 1024 blocks).
__global__ __launch_bounds__(256) void fused_pre_k(const float* __restrict__ xv,
                                                   const float* __restrict__ xk,
                                                   const float* __restrict__ xq,
                                                   const float* __restrict__ Wv,
                                                   const float* __restrict__ Wk,
                                                   const float* __restrict__ Wq,
                                                   __hip_bfloat16* __restrict__ ov,
                                                   __hip_bfloat16* __restrict__ ok,
                                                   __hip_bfloat16* __restrict__ oq,
                                                   const int* __restrict__ mask,
                                                   u64* __restrict__ bits,
                                                   const float* __restrict__ Wo,
                                                   __hip_bfloat16* __restrict__ wob,
                                                   float qscale) {
  int which = blockIdx.y;
  int t = threadIdx.x;
  int row = blockIdx.x;            // n*SEQ + l
  if (which == 3) {
    // ---- mask pack: bits[n][kb][q], 1 uint64 per 64 keys
    int n = row >> 11, q = row & 2047;
    int lane = t & 63, wv = t >> 6;
    const int* m = mask + (size_t)row * SEQ;
    for (int w = wv; w < SEQ / 64; w += 4) {
      int v = m[w * 64 + lane];
      u64 bal = __ballot(v != 0);
      if (lane == 0) bits[((size_t)n * 32 + w) * 2048 + q] = bal;
    }
    // ---- Wo cvt on first 1024 blocks
    if (row < 1024) {
      int i = (row * 256 + t) * 4;
      float4 v = *(const float4*)(Wo + i);
      wob[i + 0] = __float2bfloat16(v.x);
      wob[i + 1] = __float2bfloat16(v.y);
      wob[i + 2] = __float2bfloat16(v.z);
      wob[i + 3] = __float2bfloat16(v.w);
    }
    return;
  }
  __shared__ __align__(16) float Ws4[64 * 17 * 4];  // W rows as float4, padded (R11-proven)
  __shared__ __align__(16) float xs[1024];
  const float* x = (which == 0) ? xv : (which == 1) ? xk : xq;
  const float* W = (which == 0) ? Wv : (which == 1) ? Wk : Wq;
  __hip_bfloat16* out = (which == 0) ? ov : (which == 1) ? ok : oq;
  float scale = (which == 2) ? qscale : 1.0f;

  int n = row >> 11, l = row & 2047;
  const float4* W4 = (const float4*)W;
#pragma unroll
  for (int i = 0; i < 4; ++i) {
    int f4 = i * 256 + t;                 // f4 = d*16 + dd4
    int d = f4 >> 4, dd4 = f4 & 15;
    *(float4*)&Ws4[(d * 17 + dd4) * 4] = W4[f4];
  }
  float4 v = ((const float4*)(x + (size_t)row * EMB))[t];
  *(float4*)&xs[t * 4] = v;
  __syncthreads();
  int d = t & 63, wv = t >> 6;
  float s[4] = {0.f, 0.f, 0.f, 0.f};
#pragma unroll
  for (int dd4 = 0; dd4 < 16; ++dd4) {
    float4 wv4 = *(const float4*)&Ws4[(d * 17 + dd4) * 4];
#pragma unroll
    for (int i = 0; i < 4; ++i) {
      float4 xv4 = *(const float4*)&xs[(i * 4 + wv) * 64 + dd4 * 4];
      s[i] += xv4.x * wv4.x + xv4.y * wv4.y + xv4.z * wv4.z + xv4.w * wv4.w;
    }
  }
#pragma unroll
  for (int i = 0; i < 4; ++i) {
    int h = i * 4 + wv;
    out[((size_t)(n * NH + h) * SEQ + l) * HD + d] = __float2bfloat16(s[i] * scale);
  }
}

// ---------------- V transpose: vp[nh][key][d] -> vT[nh][d][granule-permuted keys] ----
// 8B granule g (4 keys) of row d stored at slot g ^ (d & 15) within each 128B tile seg.
__global__ __launch_bounds__(256) void transpose_v_k(const __hip_bfloat16* __restrict__ vp,
                                                     __hip_bfloat16* __restrict__ vT) {
  __shared__ __align__(16) u16 Ls[64 * 64];   // [key][d], XOR-swizzled 16B chunks
  int t = threadIdx.x;
  int kt = blockIdx.x, nh = blockIdx.y;
  const u16* src = (const u16*)(vp + ((size_t)nh * SEQ + kt * 64) * HD);
#pragma unroll
  for (int p = 0; p < 2; ++p) {
    int key = p * 32 + (t >> 3);
    int dc = t & 7;                         // 16B chunk within row
    uint4 vv = *(const uint4*)(src + key * 64 + dc * 8);
    *(uint4*)((char*)Ls + key * 128 + ((dc ^ (key & 7)) * 16)) = vv;
  }
  __syncthreads();
  u16* dst = (u16*)(vT + (size_t)nh * HD * SEQ);
#pragma unroll
  for (int p = 0; p < 2; ++p) {
    int d = p * 32 + (t >> 3);
    int kc = t & 7;                         // key chunk (8 keys = granules 2kc, 2kc+1)
    union { u16 s[8]; uint4 v4; } u;
#pragma unroll
    for (int j = 0; j < 8; ++j) {
      int key = kc * 8 + j;
      u.s[j] = *(const u16*)((const char*)Ls + key * 128 + (((d >> 3) ^ (key & 7)) * 16) + (d & 7) * 2);
    }
    u16* dstrow = dst + (size_t)d * SEQ + kt * 64;
    int x = d & 15;
    uint2 a = {u.v4.x, u.v4.y};
    uint2 b = {u.v4.z, u.v4.w};
    *(uint2*)(dstrow + (((2 * kc) ^ x) * 4))     = a;
    *(uint2*)(dstrow + (((2 * kc + 1) ^ x) * 4)) = b;
  }
}

// ---------------- flash attention (R11 + MFMA C-operand seeding, isolated) ----------------
// S^T swapped ops, register P, dbuf LDS, defer-max THR=8, cross-tile MFMA
// row-sum, mask prefetch, XCD-aware block swizzle. Isolated change vs R11:
// first QK MFMA takes persistent negm4 as C-in (no per-tile accumulator movs).
__global__ __launch_bounds__(256) void attn_k(const __hip_bfloat16* __restrict__ qp,
                                              const __hip_bfloat16* __restrict__ kp,
                                              const __hip_bfloat16* __restrict__ vT,
                                              const u64* __restrict__ mbits,
                                              __hip_bfloat16* __restrict__ obuf) {
  __shared__ __align__(16) __hip_bfloat16 Kt[2][64 * 64];    // [key][kdim] chunk-swz
  __shared__ __align__(16) __hip_bfloat16 Vt[2][64 * 64];    // [d][key] granule-swz
  int t = threadIdx.x, lane = t & 63, w = t >> 6;
  // XCD swizzle (bijective rotation of the flat block id)
  int flat = blockIdx.y * 32 + blockIdx.x;
  int nf = (flat & 7) * 256 + (flat >> 3);
  int qb = nf & 31, nh = nf >> 5;
  int n = nh >> 4, h = nh & 15;
  const __hip_bfloat16* Qg = qp + ((size_t)nh * SEQ + qb * 64) * HD;
  const char* Kg = (const char*)(kp + (size_t)nh * SEQ * HD);
  const char* Vg = (const char*)(vT + (size_t)nh * HD * SEQ);
  int l15 = lane & 15, l4 = lane >> 4;
  int e7 = l15 & 7;

  int srow = t >> 3;
  int schunk = (t & 7) ^ (srow & 7);       // K-tile source pre-swizzle (16B chunks)

  // Q B-frag: col=l15 (q=w*16+l15), k = 32c + l4*8 + j
  bf16x8 qf[2];
#pragma unroll
  for (int c = 0; c < 2; ++c)
    qf[c] = *(const bf16x8*)(Qg + (size_t)(w * 16 + l15) * HD + c * 32 + l4 * 8);

  const bf16x4 ones4 = {(short)0x3F80, (short)0x3F80, (short)0x3F80, (short)0x3F80};

  f32x4 of[4];
#pragma unroll
  for (int dt = 0; dt < 4; ++dt)
#pragma unroll
    for (int j = 0; j < 4; ++j) of[dt][j] = 0.f;
  f32x4 rs = {0.f, 0.f, 0.f, 0.f};   // cross-tile row-sum accumulator (all rows equal)
  float negm = 0.f;                  // = -m; m starts at 0 (defer-max reference)
  f32x4 negm4 = {0.f, 0.f, 0.f, 0.f};   // persistent QK C-in seed

  int q = qb * 64 + w * 16 + l15;

  // staging base pointers (per-tile offsets added in STAGE)
  const char* gk0 = Kg + srow * 128 + schunk * 16;            // + kt*8192
  const char* gv0 = Vg + (size_t)srow * 4096 + (t & 7) * 16;  // + kt*128

  auto STAGE = [&](int b, int kt) {
    const char* gk = gk0 + (size_t)kt * 8192;
    const char* gv = gv0 + (size_t)kt * 128;
    char* dk = (char*)&Kt[b][0] + w * 1024;
    char* dv = (char*)&Vt[b][0] + w * 1024;
    load_lds_16B(gk, dk);
    load_lds_16B(gk + 4096, dk + 4096);
    load_lds_16B(gv, dv);
    load_lds_16B(gv + (size_t)32 * 4096, dv + 4096);
  };

  // PV A-frag granule offsets: byte = row*128 + ((ct*4+l4)^l15)*8
  int voff[4];
#pragma unroll
  for (int ct = 0; ct < 4; ++ct)
    voff[ct] = (((ct * 4 + l4) ^ l15) * 8);

  // prologue
  const u64* mptr = mbits + (size_t)n * 32 * 2048 + q;
  STAGE(0, 0);
  u64 mw = mptr[0];
  asm volatile("s_waitcnt vmcnt(0)" ::: "memory");
  __syncthreads();

#pragma unroll 2
  for (int kt = 0; kt < NT; ++kt) {
    int cur = kt & 1;
    u64 mw_nxt = 0;
    if (kt < NT - 1) {
      STAGE(cur ^ 1, kt + 1);
      mw_nxt = mptr[(size_t)(kt + 1) * 2048];   // prefetch next tile's mask word
    }
    const char* KB = (const char*)&Kt[cur][0];
    const char* VB = (const char*)&Vt[cur][0];

    // ---- S^T = K Q^T; C-in = negm4 (persistent) => sf = s - m after MFMA
    f32x4 sf[4];
#pragma unroll
    for (int ct = 0; ct < 4; ++ct) {
      int krow = ct * 16 + l15;
      bf16x8 ak = *(const bf16x8*)(KB + krow * 128 + ((l4 ^ e7) * 16));
      sf[ct] = __builtin_amdgcn_mfma_f32_16x16x32_bf16(ak, qf[0], negm4, 0, 0, 0);
    }
#pragma unroll
    for (int ct = 0; ct < 4; ++ct) {
      int krow = ct * 16 + l15;
      bf16x8 ak = *(const bf16x8*)(KB + krow * 128 + (((4 + l4) ^ e7) * 16));
      sf[ct] = __builtin_amdgcn_mfma_f32_16x16x32_bf16(ak, qf[1], sf[ct], 0, 0, 0);
    }

    // ---- defer-max: rescale only if some lane's tile max exceeds THR=8
    float t0 = m3(sf[0][0], sf[0][1], sf[0][2]);
    float t1 = m3(sf[0][3], sf[1][0], sf[1][1]);
    float t2 = m3(sf[1][2], sf[1][3], sf[2][0]);
    float t3 = m3(sf[2][1], sf[2][2], sf[2][3]);
    float t4 = m3(sf[3][0], sf[3][1], sf[3][2]);
    float tmax = fmaxf(m3(t0, t1, t2), m3(t3, t4, sf[3][3]));
    if (__any(tmax > 8.f)) {
      float tm = fmaxf(tmax, __shfl_xor(tmax, 16));
      tm = fmaxf(tm, __shfl_xor(tm, 32));
      float d = fmaxf(tm, 0.f);                 // per-q delta (0 if no new max)
      float corr = __builtin_amdgcn_exp2f(-d);
      negm -= d;
      negm4[0] = negm; negm4[1] = negm; negm4[2] = negm; negm4[3] = negm;
#pragma unroll
      for (int j = 0; j < 4; ++j) rs[j] *= corr;
#pragma unroll
      for (int dt = 0; dt < 4; ++dt)
#pragma unroll
        for (int r = 0; r < 4; ++r) of[dt][r] *= corr;
#pragma unroll
      for (int ct = 0; ct < 4; ++ct)
#pragma unroll
        for (int r = 0; r < 4; ++r) sf[ct][r] -= d;
    }
    // ---- p = exp2(sf) (<= 2^8), mask-zero (bit 16ct + 4*l4 + r), pack to bf16
    u64 m4 = mw >> (l4 * 4);
    u32 c0 = (u32)m4, c1 = (u32)(m4 >> 32);
    bf16x4 pbq[4];
#pragma unroll
    for (int ct = 0; ct < 4; ++ct) {
      u32 sel = (ct & 2) ? c1 : c0;
      u32 base = (ct & 1) ? 0x10000u : 1u;
      float p0 = __builtin_amdgcn_exp2f(sf[ct][0]);
      float p1 = __builtin_amdgcn_exp2f(sf[ct][1]);
      float p2 = __builtin_amdgcn_exp2f(sf[ct][2]);
      float p3 = __builtin_amdgcn_exp2f(sf[ct][3]);
      p0 = (sel & (base << 0)) ? p0 : 0.f;
      p1 = (sel & (base << 1)) ? p1 : 0.f;
      p2 = (sel & (base << 2)) ? p2 : 0.f;
      p3 = (sel & (base << 3)) ? p3 : 0.f;
      union { u32 u[2]; bf16x4 s; } pu;
      pu.u[0] = pk2(p0, p1);
      pu.u[1] = pk2(p2, p3);
      pbq[ct] = pu.s;
    }
    // ---- row-sum accumulates across tiles (A = ones => all C rows identical)
#pragma unroll
    for (int ct = 0; ct < 4; ++ct)
      rs = __builtin_amdgcn_mfma_f32_16x16x16bf16_1k(ones4, pbq[ct], rs, 0, 0, 0);
    // ---- O^T += V^T P : A = V^T b64 granule frags (conflict-free), B = register P
#pragma unroll
    for (int dt = 0; dt < 4; ++dt) {
      int vrow_b = (dt * 16 + l15) * 128;
#pragma unroll
      for (int ct = 0; ct < 4; ++ct) {
        bf16x4 av = *(const bf16x4*)(VB + vrow_b + voff[ct]);
        of[dt] = __builtin_amdgcn_mfma_f32_16x16x16bf16_1k(av, pbq[ct], of[dt], 0, 0, 0);
      }
    }

    mw = mw_nxt;
    if (kt < NT - 1) {
      asm volatile("s_waitcnt vmcnt(0)" ::: "memory");   // next-tile stage landed
      __syncthreads();
    }
  }
  // ---- epilogue: lane owns q; d = 16dt + 4*l4 + r (8B packed stores)
  float inv = 1.f / rs[0];
  size_t obase = ((size_t)n * SEQ + q) * EMB + h * HD;
#pragma unroll
  for (int dt = 0; dt < 4; ++dt) {
    uint2 v2 = {pk2(of[dt][0] * inv, of[dt][1] * inv),
                pk2(of[dt][2] * inv, of[dt][3] * inv)};
    *(uint2*)(obuf + obase + dt * 16 + l4 * 4) = v2;
  }
}

// ---------------- output GEMM: double-buffered, chunk-swizzled ----------------
__global__ __launch_bounds__(256) void out_gemm_k(const __hip_bfloat16* __restrict__ A,
                                                  const __hip_bfloat16* __restrict__ Bw,
                                                  const float* __restrict__ bias,
                                                  float* __restrict__ Y) {
  __shared__ __align__(16) __hip_bfloat16 As[2][128 * 32];
  __shared__ __align__(16) __hip_bfloat16 Bs[2][128 * 32];
  int t = threadIdx.x, lane = t & 63, w = t >> 6;
  int l15 = lane & 15, l4 = lane >> 4;
  int bm = blockIdx.x * 128, bn = blockIdx.y * 128;
  int wr = w >> 1, wc = w & 1;
  f32x4 acc[4][4];
#pragma unroll
  for (int m = 0; m < 4; ++m)
#pragma unroll
    for (int nn = 0; nn < 4; ++nn)
#pragma unroll
      for (int j = 0; j < 4; ++j) acc[m][nn][j] = 0.f;

  int srow = t >> 2;                        // LDS row 0..63 (row stride 64B)
  int schunk = (t & 3) ^ (srow & 3);        // source 16B chunk pre-swizzle

  auto STAGE = [&](int b, int kt) {
    const char* ga = (const char*)(A + (size_t)(bm + srow) * 1024 + kt * 32) + schunk * 16;
    char* da = (char*)&As[b][0] + w * 1024;
    load_lds_16B(ga, da);
    load_lds_16B(ga + (size_t)64 * 2048, da + 4096);   // rows +64: same (row&3)
    const char* gb = (const char*)(Bw + (size_t)(bn + srow) * 1024 + kt * 32) + schunk * 16;
    char* db = (char*)&Bs[b][0] + w * 1024;
    load_lds_16B(gb, db);
    load_lds_16B(gb + (size_t)64 * 2048, db + 4096);
  };

  STAGE(0, 0);
  asm volatile("s_waitcnt vmcnt(0)" ::: "memory");
  __syncthreads();

#pragma unroll 2
  for (int kt = 0; kt < 32; ++kt) {
    int cur = kt & 1;
    if (kt < 31) STAGE(cur ^ 1, kt + 1);
    const char* AB = (const char*)&As[cur][0];
    const char* BB = (const char*)&Bs[cur][0];
    bf16x8 af[4], bfr[4];
#pragma unroll
    for (int m = 0; m < 4; ++m) {
      int arow = wr * 64 + m * 16 + l15;
      af[m] = *(const bf16x8*)(AB + arow * 64 + ((l4 ^ (arow & 3)) * 16));
    }
#pragma unroll
    for (int nn = 0; nn < 4; ++nn) {
      int brow = wc * 64 + nn * 16 + l15;
      bfr[nn] = *(const bf16x8*)(BB + brow * 64 + ((l4 ^ (brow & 3)) * 16));
    }
#pragma unroll
    for (int m = 0; m < 4; ++m)
#pragma unroll
      for (int nn = 0; nn < 4; ++nn)
        acc[m][nn] = __builtin_amdgcn_mfma_f32_16x16x32_bf16(af[m], bfr[nn], acc[m][nn], 0, 0, 0);
    if (kt < 31) {
      asm volatile("s_waitcnt vmcnt(0)" ::: "memory");
      __syncthreads();
    }
  }
#pragma unroll
  for (int m = 0; m < 4; ++m)
#pragma unroll
    for (int nn = 0; nn < 4; ++nn)
#pragma unroll
      for (int r = 0; r < 4; ++r) {
        int row = bm + wr * 64 + m * 16 + l4 * 4 + r;
        int col = bn + wc * 64 + nn * 16 + l15;
        Y[(size_t)row * 1024 + col] = acc[m][nn][r] + bias[col];
      }
}

extern "C" void kernel_launch(void* const* d_in, const int* in_sizes, int n_in,
                              void* d_out, int out_size, void* d_ws, size_t ws_size,
                              hipStream_t stream) {
  const float* values  = (const float*)d_in[0];
  const float* keys    = (const float*)d_in[1];
  const float* queries = (const float*)d_in[2];
  const int*   mask    = (const int*)d_in[3];
  const float* Wv      = (const float*)d_in[4];
  const float* Wk      = (const float*)d_in[5];
  const float* Wq      = (const float*)d_in[6];
  const float* Wo      = (const float*)d_in[7];
  const float* bo      = (const float*)d_in[8];
  float* out = (float*)d_out;

  char* ws = (char*)d_ws;
  __hip_bfloat16* qp   = (__hip_bfloat16*)(ws);
  __hip_bfloat16* kp   = (__hip_bfloat16*)(ws + (size_t)16 * 1024 * 1024);
  __hip_bfloat16* vp   = (__hip_bfloat16*)(ws + (size_t)32 * 1024 * 1024);
  __hip_bfloat16* obuf = (__hip_bfloat16*)(ws + (size_t)48 * 1024 * 1024);
  u64*            mbts = (u64*)           (ws + (size_t)64 * 1024 * 1024);
  __hip_bfloat16* wob  = (__hip_bfloat16*)(ws + (size_t)66 * 1024 * 1024);
  __hip_bfloat16* vTp  = (__hip_bfloat16*)(ws + (size_t)80 * 1024 * 1024);

  // Q pre-scale: (1/sqrt(EMB)) * log2(e) so attn softmax runs in exp2 domain
  const float qscale = 0.03125f * 1.44269504088896340736f;

  fused_pre_k<<<dim3(N_B * SEQ, 4), 256, 0, stream>>>(values, keys, queries,
                                                      Wv, Wk, Wq, vp, kp, qp,
                                                      mask, mbts, Wo, wob, qscale);
  transpose_v_k<<<dim3(SEQ / 64, N_B * NH), 256, 0, stream>>>(vp, vTp);
  attn_k<<<dim3(32, 64), 256, 0, stream>>>(qp, kp, vTp, mbts, obuf);
  out_gemm_k<<<dim3(64, 8), 256, 0, stream>>>(obuf, wob, bo, out);
}